// Round 11
// baseline (670.173 us; speedup 1.0000x reference)
//
#include <hip/hip_runtime.h>
#include <math.h>

#define NX   160
#define N2   25600        // 160*160
#define N3   4096000      // 160^3
#define NB   4

#define NBLK 1600         // single grid; 7 blocks/CU x 256 CU = 1792 >= 1600
#define ABLK_PER_B 400    // phase-A blocks per batch
#define AF4  2560         // float4 elements per phase-A block

#define XT   8            // f4 columns per fused tile (32 x)
#define XTP  10           // padded row stride in f4
#define YT   32           // y rows per fused tile
#define ZCH  10           // z outputs per block
#define SROWS 40          // YT + 8 (y halo)

// 1D Gaussian taps exp(-d^2/50), d=-4..4 (NOT normalized, matches reference)
__device__ __constant__ float G1[9] = {
    0.72614903f, 0.83527021f, 0.92311635f, 0.98019867f, 1.0f,
    0.98019867f, 0.92311635f, 0.83527021f, 0.72614903f};

// edge sums: FULL - missing taps at low/high boundary
#define ES_FULL 7.92946852f
__device__ __constant__ float ES_M[4] = {3.46473426f, 2.48453559f, 1.56141924f,
                                         0.72614903f};
__device__ inline float edge_sum(int i) {
    float s = ES_FULL;
    if (i < 4) s -= ES_M[i];
    if (i > NX - 5) s -= ES_M[NX - 1 - i];
    return s;
}

__device__ inline float4 f4_zero() { return make_float4(0.f, 0.f, 0.f, 0.f); }
__device__ inline float4 f4_axpy(float a, float4 b, float4 c) {
    return make_float4(c.x + a * b.x, c.y + a * b.y, c.z + a * b.z, c.w + a * b.w);
}

// block reduce NV doubles -> device-scope atomicAdd into dst[0..NV).
// Keep-alive on the returned value forces the waitcnt, so the add is
// globally complete before this thread passes the following barrier.
template <int NV>
__device__ inline void block_reduce_atomic(double* vals, double* dst) {
    __shared__ double red[4][NV];
    int lane = threadIdx.x & 63;
    int wave = threadIdx.x >> 6;
#pragma unroll
    for (int v = 0; v < NV; ++v) {
        double x = vals[v];
#pragma unroll
        for (int off = 32; off > 0; off >>= 1) x += __shfl_down(x, off, 64);
        if (lane == 0) red[wave][v] = x;
    }
    __syncthreads();
    if (threadIdx.x < NV) {
        double part = red[0][threadIdx.x] + red[1][threadIdx.x] +
                      red[2][threadIdx.x] + red[3][threadIdx.x];
        double old = atomicAdd(&dst[threadIdx.x], part);
        asm volatile("" :: "v"(old));   // force completion ordering
    }
    __syncthreads();
}

// raw 12-float row segment (3 guarded float4) for staged row (gy, f4-col gc)
__device__ inline void load_row_raw(const float* __restrict__ lbase, int zp,
                                    int gy, int gc, float4* r) {
    bool ok = (zp >= 0) && (zp < NX) && (gy >= 0) && (gy < NX);
    const float* row = lbase + zp * N2 + gy * NX;
#pragma unroll
    for (int c = 0; c < 3; ++c) {
        int g4 = gc - 1 + c;
        r[c] = (ok && g4 >= 0 && g4 < 40) ? *(const float4*)&row[4 * g4]
                                          : f4_zero();
    }
}

// x-conv: 12 raw floats (3 f4) -> 4 outputs
__device__ inline float4 xconv_regs(const float4* r) {
    float w[12] = {r[0].x, r[0].y, r[0].z, r[0].w, r[1].x, r[1].y,
                   r[1].z, r[1].w, r[2].x, r[2].y, r[2].z, r[2].w};
    float4 o = f4_zero();
#pragma unroll
    for (int kk = 0; kk < 9; ++kk) {
        float g = G1[kk];
        o.x += g * w[kk];     o.y += g * w[kk + 1];
        o.z += g * w[kk + 2]; o.w += g * w[kk + 3];
    }
    return o;
}

__device__ inline float4 ydot9(const float4 (*sb)[XTP], int oy, int ox) {
    float4 w8 = f4_zero();
#pragma unroll
    for (int dy = 0; dy < 9; ++dy) w8 = f4_axpy(G1[dy], sb[oy + dy][ox], w8);
    return w8;
}

// R14: single-kernel pipeline with manual device-scope barrier.
//  phase A: streaming batch sums -> atomicAdd SA[12]; spin on cntA.
//  phase B: R13 fused conv (ZCH=10, 1600 blocks -> ~7 blocks/CU, 87% occ),
//           means read straight from SA; partials -> atomicAdd Z[4].
//  phase C: LAST block (cntB ticket) computes the loss. No inter-dispatch
//  boundaries (R13: kernel-sum ~135us vs 243us total).
// Co-residency: launch_bounds(256,7) -> VGPR<=73 (R13 used 64), LDS 13KB;
// 7 blk/CU * 256 CU = 1792 >= 1600 -> spin barrier cannot deadlock.
__global__ __launch_bounds__(256, 7) void mono_kernel(
    const float* __restrict__ labels, const float* __restrict__ inputs,
    double* __restrict__ SA, double* __restrict__ Z,
    unsigned int* __restrict__ cntA, unsigned int* __restrict__ cntB,
    float* __restrict__ out) {
    int tid = threadIdx.x;
    int bid = blockIdx.x;

    // ---------------- phase A: per-batch sums ----------------
    {
        int ab = bid / ABLK_PER_B;       // batch 0..3
        int chunk = bid % ABLK_PER_B;
        const float4* lp = (const float4*)(labels + ab * N3) + chunk * AF4;
        const float4* ip = (const float4*)(inputs + ab * N3) + chunk * AF4;
        double sp = 0.0, sip = 0.0, si = 0.0;
        for (int i = tid; i < AF4; i += 256) {
            float4 p = lp[i];
            float4 in = ip[i];
            sp += (double)(p.x + p.y + p.z + p.w);
            sip += (double)(in.x * p.x + in.y * p.y + in.z * p.z + in.w * p.w);
            si += (double)(in.x + in.y + in.z + in.w);
        }
        double vals[3] = {sp, sip, si};
        block_reduce_atomic<3>(vals, SA + 3 * ab);
        if (tid == 0) {
            unsigned int o = atomicAdd(cntA, 1u);
            asm volatile("" :: "v"(o));
            while (__hip_atomic_load(cntA, __ATOMIC_RELAXED,
                                     __HIP_MEMORY_SCOPE_AGENT) < NBLK)
                __builtin_amdgcn_s_sleep(8);
        }
        __syncthreads();
    }

    // means (identical values in every block: read the final accumulated SA)
    __shared__ float sM[2];
    int u = bid >> 3;
    int xcd = bid & 7;
    int xt = u % 5;
    int yt = (u / 5) % 5;
    int zs = (u / 25) % 2;
    int b = u / 50;               // 0..3, uniform per block
    if (tid == 0) {
        double sp = __hip_atomic_load(&SA[3 * b + 0], __ATOMIC_RELAXED,
                                      __HIP_MEMORY_SCOPE_AGENT);
        double sip = __hip_atomic_load(&SA[3 * b + 1], __ATOMIC_RELAXED,
                                       __HIP_MEMORY_SCOPE_AGENT);
        double si = __hip_atomic_load(&SA[3 * b + 2], __ATOMIC_RELAXED,
                                      __HIP_MEMORY_SCOPE_AGENT);
        const double Nv = (double)N3;
        sM[0] = (float)((sip / Nv) / (sp / Nv + 1e-5));
        sM[1] = (float)(((si - sip) / Nv) / ((Nv - sp) / Nv + 1e-5));
    }
    __syncthreads();
    float m0 = sM[0], m1 = sM[1];

    // ---------------- phase B: fused separable conv ----------------
    int x0f = xt * XT;            // f4 col base
    int y0 = yt * YT;
    int z0 = xcd * 20 + zs * ZCH; // XCD slab + half-slab

    int ox = tid & 7;             // f4 col within tile
    int oy = tid >> 3;            // y row within tile, 0..31
    int y = y0 + oy;
    int xo = (x0f + ox) * 4;
    float ey = edge_sum(y);
    float cx[4] = {edge_sum(xo) * ey, edge_sum(xo + 1) * ey,
                   edge_sum(xo + 2) * ey, edge_sum(xo + 3) * ey};

    const float* lbase = labels + b * N3;
    const float* ibase = inputs + b * N3;
    int po = y * NX + xo;

    int sra = tid >> 3, sca = tid & 7;          // staged row 0..31
    int srb = 32 + (tid >> 3), scb = tid & 7;   // staged row 32..39
    bool hasb = (tid < 64);
    int gya = y0 - 4 + sra, gyb = y0 - 4 + srb;
    int gca = x0f + sca, gcb = x0f + scb;

    __shared__ float4 sbuf[2][SROWS][XTP];

    {   // stage plane z0-4 into sbuf[0]
        float4 ra[3], rb[3];
        load_row_raw(lbase, z0 - 4, gya, gca, ra);
        if (hasb) load_row_raw(lbase, z0 - 4, gyb, gcb, rb);
        sbuf[0][sra][sca] = xconv_regs(ra);
        if (hasb) sbuf[0][srb][scb] = xconv_regs(rb);
    }
    __syncthreads();

    float4 win[9];
#pragma unroll
    for (int d = 0; d < 9; ++d) win[d] = f4_zero();

    float n0 = 0.f, d0 = 0.f, n1 = 0.f, d1 = 0.f;
    for (int k = 0; k < ZCH + 8; ++k) {
        int cur = k & 1, nxt = cur ^ 1;
        int zstage = z0 - 4 + k + 1;

        // 1. issue raw loads for plane k+1 (latency hides under 3-5)
        float4 ra[3], rb[3];
        load_row_raw(lbase, zstage, gya, gca, ra);
        if (hasb) load_row_raw(lbase, zstage, gyb, gcb, rb);

        // 2. center loads for output iter
        int z = z0 + k - 8;
        float4 pv = f4_zero(), iv = f4_zero();
        if (k >= 8) {
            pv = *(const float4*)&lbase[z * N2 + po];
            iv = *(const float4*)&ibase[z * N2 + po];
        }

        // 3. y-dot of plane k from LDS
        float4 w8 = ydot9(sbuf[cur], oy, ox);

        // 4. static window shift
#pragma unroll
        for (int d = 0; d < 8; ++d) win[d] = win[d + 1];
        win[8] = w8;

        // 5. pointwise accumulate
        if (k >= 8) {
            float4 c4 = f4_zero();
#pragma unroll
            for (int d = 0; d < 9; ++d) c4 = f4_axpy(G1[d], win[d], c4);
            float ez = edge_sum(z);
            float pc[4] = {pv.x, pv.y, pv.z, pv.w};
            float ic[4] = {iv.x, iv.y, iv.z, iv.w};
            float cc[4] = {c4.x, c4.y, c4.z, c4.w};
#pragma unroll
            for (int l = 0; l < 4; ++l) {
                float c1 = cx[l] * ez - cc[l];  // conv(1-p) via conv(ones)
                float df0 = ic[l] - m0; df0 *= df0;
                float w0 = __expf(-df0 * df0);
                float df1 = ic[l] - m1; df1 *= df1;
                float w1 = __expf(-df1 * df1);
                n0 += cc[l] * pc[l] * w0;
                d0 += cc[l] * w0;
                n1 += c1 * (1.f - pc[l]) * w1;
                d1 += c1 * w1;
            }
        }

        // 6. xconv in regs, write plane k+1 to sbuf[nxt]
        float4 oa = xconv_regs(ra);
        sbuf[nxt][sra][sca] = oa;
        if (hasb) {
            float4 ob = xconv_regs(rb);
            sbuf[nxt][srb][scb] = ob;
        }
        __syncthreads();   // RAW for next ydot; WAR covered by prev barrier
    }

    // ---------------- phase C: accumulate + last-block finalize ----------------
    double vals[4] = {(double)n0, (double)d0, (double)n1, (double)d1};
    block_reduce_atomic<4>(vals, Z);
    if (tid == 0) {
        unsigned int o = atomicAdd(cntB, 1u);
        if (o == NBLK - 1) {
            double a0 = __hip_atomic_load(&Z[0], __ATOMIC_RELAXED,
                                          __HIP_MEMORY_SCOPE_AGENT);
            double a1 = __hip_atomic_load(&Z[1], __ATOMIC_RELAXED,
                                          __HIP_MEMORY_SCOPE_AGENT);
            double a2 = __hip_atomic_load(&Z[2], __ATOMIC_RELAXED,
                                          __HIP_MEMORY_SCOPE_AGENT);
            double a3 = __hip_atomic_load(&Z[3], __ATOMIC_RELAXED,
                                          __HIP_MEMORY_SCOPE_AGENT);
            double r0 = fabs(a0 / (a1 + 1e-6));
            double r1 = fabs(a2 / (a3 + 1e-6));
            out[0] = (float)(2.0 - r0 - r1);
        }
    }
}

extern "C" void kernel_launch(void* const* d_in, const int* in_sizes, int n_in,
                              void* d_out, int out_size, void* d_ws, size_t ws_size,
                              hipStream_t stream) {
    const float* labels = (const float*)d_in[0];
    const float* inputs = (const float*)d_in[1];
    float* out = (float*)d_out;

    // ws layout:
    //   [0)    SA  : 12 doubles (96 B)
    //   [96)   Z   : 4 doubles (32 B)
    //   [128)  cntA: uint
    //   [132)  cntB: uint
    double* SA = (double*)d_ws;
    double* Z = (double*)((char*)d_ws + 96);
    unsigned int* cntA = (unsigned int*)((char*)d_ws + 128);
    unsigned int* cntB = (unsigned int*)((char*)d_ws + 132);

    // zero accumulators + tickets each launch (graph-capture legal)
    hipMemsetAsync(d_ws, 0, 192, stream);

    hipLaunchKernelGGL(mono_kernel, dim3(NBLK), dim3(256), 0, stream,
                       labels, inputs, SA, Z, cntA, cntB, out);
}